// Round 10
// baseline (264.038 us; speedup 1.0000x reference)
//
#include <hip/hip_runtime.h>
#include <hip/hip_fp16.h>
#include <math.h>

#define F_IN 128
#define H 16
#define C 40
#define K_HOPS 10
#define ALPHA 0.1f
#define BN_EPS 1e-5f

#define RB 256          // nodes per bucket
#define RB_BITS 8
#define NBKT_MAX 512    // ceil(100000/256)=391
#define SRC_MASK 0x1FFFF
#define PADQ 16         // node segment padded to multiple of 16 entries
#define NDUMMY 2048     // dummy zero rows spread over L2
#define CAPB_BITS 14    // fixed per-bucket capacity for temp AND csr (16384 entries)
#define CAPB (1 << CAPB_BITS)
#define STAGE_CAP 14336 // ints (56 KB) LDS staging for csr scatter
#define GR 512          // persistent gather grid

typedef int v4i __attribute__((ext_vector_type(4)));

// ---------------- zero: gcur = bucket bases, stats=0, dummy rows of both tables = 0 ----------------
__global__ void k_zero(int* __restrict__ gcur, float* __restrict__ stats,
                       __half* __restrict__ h1h, __half* __restrict__ hh, int n) {
    int id = blockIdx.x * blockDim.x + threadIdx.x;
    if (id < NBKT_MAX) gcur[id] = id << CAPB_BITS;
    if (id < 32) stats[id] = 0.0f;
    int* z1 = (int*)(h1h + (size_t)n * H);
    int* z2 = (int*)(hh + (size_t)n * H);
    if (id < NDUMMY * H / 2) { z1[id] = 0; z2[id] = 0; }
}

// ---------------- bin edges: LDS counting sort per block -> dense run writes ----------------
#define BIN_CHUNK 4096
__global__ __launch_bounds__(512) void k_bin(const int* __restrict__ src,
                                             const int* __restrict__ dst,
                                             int* __restrict__ gcur,
                                             int* __restrict__ temp, int e) {
    __shared__ int hist[NBKT_MAX];
    __shared__ int cur[NBKT_MAX];
    __shared__ int gofs[NBKT_MAX];
    __shared__ int wsum[8];
    __shared__ int stageV[BIN_CHUNK];
    __shared__ int stageD[BIN_CHUNK];
    int t = threadIdx.x;
    hist[t] = 0;
    __syncthreads();
    int base = blockIdx.x * BIN_CHUNK;
    int cnt = e - base; if (cnt > BIN_CHUNK) cnt = BIN_CHUNK;
    const v4i* s4 = reinterpret_cast<const v4i*>(src + base);
    const v4i* d4 = reinterpret_cast<const v4i*>(dst + base);
    v4i sv[2], dv[2];
#pragma unroll
    for (int i = 0; i < 2; ++i) {
        int e0 = (t * 2 + i) * 4;
        if (e0 + 3 < cnt) { sv[i] = s4[t * 2 + i]; dv[i] = d4[t * 2 + i]; }
        else if (e0 < cnt) {
            int ts[4], td[4];
#pragma unroll
            for (int j = 0; j < 4; ++j) {
                int ei = e0 + j;
                ts[j] = (ei < cnt) ? src[base + ei] : 0;
                td[j] = (ei < cnt) ? dst[base + ei] : -1;
            }
            sv[i] = *reinterpret_cast<v4i*>(ts); dv[i] = *reinterpret_cast<v4i*>(td);
        } else { dv[i] = (v4i){-1, -1, -1, -1}; sv[i] = dv[i]; }
    }
#pragma unroll
    for (int i = 0; i < 2; ++i) {
        if (dv[i].x >= 0) atomicAdd(&hist[dv[i].x >> RB_BITS], 1);
        if (dv[i].y >= 0) atomicAdd(&hist[dv[i].y >> RB_BITS], 1);
        if (dv[i].z >= 0) atomicAdd(&hist[dv[i].z >> RB_BITS], 1);
        if (dv[i].w >= 0) atomicAdd(&hist[dv[i].w >> RB_BITS], 1);
    }
    __syncthreads();
    int v = hist[t];
    int lane = t & 63, wv = t >> 6;
    int s = v;
#pragma unroll
    for (int off = 1; off < 64; off <<= 1) { int u = __shfl_up(s, off); if (lane >= off) s += u; }
    if (lane == 63) wsum[wv] = s;
    __syncthreads();
    if (t < 8) {
        int x = wsum[t];
#pragma unroll
        for (int off = 1; off < 8; off <<= 1) { int u = __shfl_up(x, off); if (t >= off) x += u; }
        wsum[t] = x;
    }
    __syncthreads();
    int excl = s - v + (wv ? wsum[wv - 1] : 0);
    cur[t] = excl;
    int g = v ? atomicAdd(&gcur[t], v) : 0;
    gofs[t] = g - excl;
    __syncthreads();
#pragma unroll
    for (int i = 0; i < 2; ++i) {
        int ds[4] = { dv[i].x, dv[i].y, dv[i].z, dv[i].w };
        int ssx[4] = { sv[i].x, sv[i].y, sv[i].z, sv[i].w };
#pragma unroll
        for (int j = 0; j < 4; ++j) {
            int d = ds[j];
            if (d >= 0) {
                int b = d >> RB_BITS;
                int pos = atomicAdd(&cur[b], 1);
                stageV[pos] = ssx[j] | ((d & (RB - 1)) << 17);
                stageD[pos] = gofs[b];
            }
        }
    }
    __syncthreads();
    for (int i = t; i < cnt; i += 512)
        temp[stageD[i] + i] = stageV[i];
}

// ---------------- per-bucket counting sort -> padded CSR (LDS-staged scatter);
//                  512 threads; deg->dinv; HEAVY-FIRST order ----------------
__global__ __launch_bounds__(512) void k_sort(const int* __restrict__ gcur,
                                              const int* __restrict__ temp,
                                              int* __restrict__ csr,
                                              int* __restrict__ ostart,
                                              int* __restrict__ oend,
                                              int* __restrict__ onode,
                                              float* __restrict__ dinv, int n) {
    __shared__ int hist[RB];
    __shared__ int cur[RB];
    __shared__ int wsum[4];
    __shared__ int qh[64];
    __shared__ int qb[64];
    __shared__ int ptotS;
    __shared__ int stage[STAGE_CAP];
    int t = threadIdx.x;
    int bkt = blockIdx.x;
    int start = bkt << CAPB_BITS;
    int endi = gcur[bkt];
    int nv = endi - start;
    int n4 = nv >> 2;
    const v4i* t4 = reinterpret_cast<const v4i*>(temp + start);
    if (t < RB) hist[t] = 0;
    if (t < 64) qh[t] = 0;
    __syncthreads();
    for (int k = t; k < n4; k += 512) {
        v4i v = t4[k];
        atomicAdd(&hist[v.x >> 17], 1);
        atomicAdd(&hist[v.y >> 17], 1);
        atomicAdd(&hist[v.z >> 17], 1);
        atomicAdd(&hist[v.w >> 17], 1);
    }
    for (int k = start + (n4 << 2) + t; k < endi; k += 512)
        atomicAdd(&hist[temp[k] >> 17], 1);
    __syncthreads();
    int node = (bkt << RB_BITS) + t;
    int h = 0, pv = 0;
    bool va = false;
    if (t < RB) {
        h = hist[t];
        pv = (h + PADQ - 1) & ~(PADQ - 1);
        va = (node < n);
        if (va) dinv[node] = rsqrtf((float)(h + 1));
    }
    int lane = t & 63, wv = t >> 6;
    int s = pv;
#pragma unroll
    for (int off = 1; off < 64; off <<= 1) { int u = __shfl_up(s, off); if (lane >= off) s += u; }
    if (lane == 63 && wv < 4) wsum[wv] = s;
    __syncthreads();
    if (t < 4) {
        int x = wsum[t];
#pragma unroll
        for (int off = 1; off < 4; off <<= 1) { int u = __shfl_up(x, off); if (t >= off) x += u; }
        wsum[t] = x;
        if (t == 3) ptotS = x;
    }
    __syncthreads();
    int pexcl = 0, s0 = 0, q = 63, r = 0;
    if (t < RB) {
        pexcl = s - pv + (wv ? wsum[wv - 1] : 0);
        s0 = start + pexcl;
        q = 63 - min(pv >> 4, 63);
        r = atomicAdd(&qh[q], 1);
    }
    __syncthreads();
    int ptotal = ptotS;
    if (t == 0) {
        int run = 0;
        for (int i = 0; i < 64; ++i) { qb[i] = run; run += qh[i]; }
    }
    __syncthreads();
    if (t < RB) {
        int ga = (bkt << RB_BITS) + qb[q] + r;
        ostart[ga] = s0; oend[ga] = s0 + pv; onode[ga] = va ? node : -1;
    }
    if (ptotal <= STAGE_CAP) {
        if (t < RB) cur[t] = pexcl;
        for (int i = t; i < ptotal; i += 512) stage[i] = -1;
        __syncthreads();
        for (int k = t; k < n4; k += 512) {
            v4i v = t4[k];
            int p0 = atomicAdd(&cur[v.x >> 17], 1); stage[p0] = v.x & SRC_MASK;
            int p1 = atomicAdd(&cur[v.y >> 17], 1); stage[p1] = v.y & SRC_MASK;
            int p2 = atomicAdd(&cur[v.z >> 17], 1); stage[p2] = v.z & SRC_MASK;
            int p3 = atomicAdd(&cur[v.w >> 17], 1); stage[p3] = v.w & SRC_MASK;
        }
        for (int k = start + (n4 << 2) + t; k < endi; k += 512) {
            int v = temp[k];
            int pos = atomicAdd(&cur[v >> 17], 1);
            stage[pos] = v & SRC_MASK;
        }
        __syncthreads();
        for (int i = t * 4; i < ptotal; i += 2048) {
            v4i v = *reinterpret_cast<const v4i*>(&stage[i]);
            int gi = start + i;
            v.x = (v.x < 0) ? n + ((gi + 0) & (NDUMMY - 1)) : v.x;
            v.y = (v.y < 0) ? n + ((gi + 1) & (NDUMMY - 1)) : v.y;
            v.z = (v.z < 0) ? n + ((gi + 2) & (NDUMMY - 1)) : v.z;
            v.w = (v.w < 0) ? n + ((gi + 3) & (NDUMMY - 1)) : v.w;
            *reinterpret_cast<v4i*>(&csr[gi]) = v;
        }
    } else {
        if (t < RB) cur[t] = s0;
        __syncthreads();
        for (int k = start + t; k < endi; k += 512) {
            int v = temp[k];
            int pos = atomicAdd(&cur[v >> 17], 1);
            csr[pos] = v & SRC_MASK;
        }
        __syncthreads();
        if (t < RB) for (int i = s0 + h; i < s0 + pv; ++i) csr[i] = n + (i & (NDUMMY - 1));
    }
}

// ---------------- h1' = dinv .* (x @ W1) -> fp16 table ----------------
__global__ __launch_bounds__(256) void k_mm1(const float* __restrict__ x,
                                             const float* __restrict__ W1,
                                             const float* __restrict__ dinv,
                                             __half* __restrict__ h1h, int n) {
    __shared__ __align__(16) float xs[16 * 132];
    __shared__ __align__(16) float ws[128 * 16];
    int t = threadIdx.x;
    int node0 = blockIdx.x * 16;
    const float4* x4 = reinterpret_cast<const float4*>(x);
    const float4* w4 = reinterpret_cast<const float4*>(W1);
#pragma unroll
    for (int r = 0; r < 2; ++r) {
        int f = t + r * 256;
        int nl = f >> 5, k4 = f & 31;
        int nn = node0 + nl; if (nn >= n) nn = n - 1;
        *reinterpret_cast<float4*>(&xs[nl * 132 + k4 * 4]) = x4[(size_t)nn * 32 + k4];
        *reinterpret_cast<float4*>(&ws[f * 4]) = w4[f];
    }
    __syncthreads();
    int nl = t >> 4, j = t & 15;
    float acc = 0.0f;
#pragma unroll 8
    for (int k = 0; k < 128; ++k)
        acc = fmaf(xs[nl * 132 + k], ws[k * 16 + j], acc);
    int node = node0 + nl;
    if (node < n) h1h[(size_t)node * H + j] = __float2half(acc * dinv[node]);
}

__device__ __forceinline__ void acc8(float* a, int4 gv) {
    const __half2* h = reinterpret_cast<const __half2*>(&gv);
    float2 f0 = __half22float2(h[0]);
    float2 f1 = __half22float2(h[1]);
    float2 f2 = __half22float2(h[2]);
    float2 f3 = __half22float2(h[3]);
    a[0] += f0.x; a[1] += f0.y; a[2] += f1.x; a[3] += f1.y;
    a[4] += f2.x; a[5] += f2.y; a[6] += f3.x; a[7] += f3.y;
}

// ---------------- gather conv1: persistent grid-stride, 4 lanes/node (2 pairs),
//                  prefetch-pipelined csr; + bias + ReLU + BN stats ----------------
__global__ __launch_bounds__(256) void k_gather1(const int* __restrict__ ostart,
                                                 const int* __restrict__ oend,
                                                 const int* __restrict__ onode,
                                                 const int* __restrict__ csr,
                                                 const __half* __restrict__ h1h,
                                                 const float* __restrict__ dinv,
                                                 const float* __restrict__ b1,
                                                 float* __restrict__ hout,
                                                 float* __restrict__ stats, int nG, int n) {
    __shared__ float sm[32];
    __shared__ float b1s[16];
    int t = threadIdx.x;
    if (t < 32) sm[t] = 0.0f;
    if (t < 16) b1s[t] = b1[t];
    __syncthreads();
    int L = t & 3, p = L >> 1, jj = L & 1;
    const int4* tab = reinterpret_cast<const int4*>(h1h);
    const v4i* csr4 = reinterpret_cast<const v4i*>(csr);
    float bs1[8], bs2[8];
#pragma unroll
    for (int k = 0; k < 8; ++k) { bs1[k] = 0.0f; bs2[k] = 0.0f; }
    for (int gBase = blockIdx.x * 64; gBase < nG; gBase += GR * 64) {
        int g = gBase + (t >> 2);
        int node = __builtin_nontemporal_load(onode + g);
        float a[8];
#pragma unroll
        for (int k = 0; k < 8; ++k) a[k] = 0.0f;
        if (node >= 0) {
            int c  = (__builtin_nontemporal_load(ostart + g) >> 2) + (p << 1);
            int ce = __builtin_nontemporal_load(oend + g) >> 2;
            v4i e0 = (v4i){0, 0, 0, 0}, e1 = e0;
            if (c < ce) { e0 = __builtin_nontemporal_load(csr4 + c); e1 = __builtin_nontemporal_load(csr4 + c + 1); }
            while (c < ce) {
                v4i f0 = e0, f1 = e1;
                c += 4;
                if (c < ce) { e0 = __builtin_nontemporal_load(csr4 + c); e1 = __builtin_nontemporal_load(csr4 + c + 1); }
                int4 g0 = tab[(size_t)f0.x * 2 + jj];
                int4 g1 = tab[(size_t)f0.y * 2 + jj];
                int4 g2 = tab[(size_t)f0.z * 2 + jj];
                int4 g3 = tab[(size_t)f0.w * 2 + jj];
                int4 g4 = tab[(size_t)f1.x * 2 + jj];
                int4 g5 = tab[(size_t)f1.y * 2 + jj];
                int4 g6 = tab[(size_t)f1.z * 2 + jj];
                int4 g7 = tab[(size_t)f1.w * 2 + jj];
                acc8(a, g0); acc8(a, g1); acc8(a, g2); acc8(a, g3);
                acc8(a, g4); acc8(a, g5); acc8(a, g6); acc8(a, g7);
            }
        }
#pragma unroll
        for (int k = 0; k < 8; ++k) a[k] += __shfl_xor(a[k], 2);
        float din = 0.0f;
        int4 sv = make_int4(0, 0, 0, 0);
        if (node >= 0) {
            din = dinv[node];
            sv = tab[(size_t)node * 2 + jj];
        }
        {
            const __half2* h = reinterpret_cast<const __half2*>(&sv);
            float2 f0 = __half22float2(h[0]), f1 = __half22float2(h[1]);
            float2 f2 = __half22float2(h[2]), f3 = __half22float2(h[3]);
            float s8[8] = { f0.x, f0.y, f1.x, f1.y, f2.x, f2.y, f3.x, f3.y };
            bool writer = (node >= 0) && (p == 0);
            float v[8];
#pragma unroll
            for (int k = 0; k < 8; ++k) {
                float val = fmaxf(din * (a[k] + s8[k]) + b1s[jj * 8 + k], 0.0f);
                v[k] = writer ? val : 0.0f;
                bs1[k] += v[k];
                bs2[k] += v[k] * v[k];
            }
            if (writer) {
                float4* o = reinterpret_cast<float4*>(hout + (size_t)node * H + jj * 8);
                o[0] = make_float4(v[0], v[1], v[2], v[3]);
                o[1] = make_float4(v[4], v[5], v[6], v[7]);
            }
        }
    }
    // single BN-stat reduction per block
#pragma unroll
    for (int k = 0; k < 8; ++k) {
        float s1 = bs1[k], s2 = bs2[k];
        s1 += __shfl_xor(s1, 2);  s2 += __shfl_xor(s2, 2);
        s1 += __shfl_xor(s1, 4);  s2 += __shfl_xor(s2, 4);
        s1 += __shfl_xor(s1, 8);  s2 += __shfl_xor(s2, 8);
        s1 += __shfl_xor(s1, 16); s2 += __shfl_xor(s2, 16);
        s1 += __shfl_xor(s1, 32); s2 += __shfl_xor(s2, 32);
        if ((t & 63) < 2) {
            atomicAdd(&sm[jj * 8 + k], s1);
            atomicAdd(&sm[16 + jj * 8 + k], s2);
        }
    }
    __syncthreads();
    if (t < 32) atomicAdd(&stats[t], sm[t]);
}

// ---------------- BN(coef inline) apply + K_HOPS residual blocks -> scaled fp16 table ----------------
__global__ __launch_bounds__(256) void k_hops(const float* __restrict__ h,
                                              __half* __restrict__ hh,
                                              const float* __restrict__ stats,
                                              const float* __restrict__ gamma,
                                              const float* __restrict__ beta,
                                              const float* __restrict__ Wl,
                                              const float* __restrict__ bl,
                                              const float* __restrict__ dinv, int n, float nf) {
    __shared__ float wl[256], bls[16], av[16], cv[16];
    int t = threadIdx.x;
    wl[t] = Wl[(t & 15) * 16 + (t >> 4)];
    if (t < 16) {
        bls[t] = bl[t];
        float mean = stats[t] / nf;
        float var = stats[16 + t] / nf - mean * mean;
        float aa = gamma[t] * rsqrtf(var + BN_EPS);
        av[t] = aa;
        cv[t] = beta[t] - mean * aa;
    }
    __syncthreads();
    int node = blockIdx.x * 256 + t;
    if (node >= n) return;
    float hr[16];
    {
        const float4* hp = reinterpret_cast<const float4*>(h + (size_t)node * H);
        float4 v0 = hp[0], v1 = hp[1], v2 = hp[2], v3 = hp[3];
        hr[0] = v0.x; hr[1] = v0.y; hr[2] = v0.z; hr[3] = v0.w;
        hr[4] = v1.x; hr[5] = v1.y; hr[6] = v1.z; hr[7] = v1.w;
        hr[8] = v2.x; hr[9] = v2.y; hr[10] = v2.z; hr[11] = v2.w;
        hr[12] = v3.x; hr[13] = v3.y; hr[14] = v3.z; hr[15] = v3.w;
    }
#pragma unroll
    for (int j = 0; j < 16; ++j) hr[j] = hr[j] * av[j] + cv[j];
    for (int it = 0; it < K_HOPS; ++it) {
        float tmp[16];
#pragma unroll
        for (int j = 0; j < 16; ++j) {
            float a = bls[j];
#pragma unroll
            for (int k = 0; k < 16; ++k) a = fmaf(hr[k], wl[j * 16 + k], a);
            tmp[j] = fmaxf(a, 0.0f);
        }
#pragma unroll
        for (int j = 0; j < 16; ++j) hr[j] = ALPHA * tmp[j] + (1.0f - ALPHA) * hr[j];
    }
    {
        float din = dinv[node];
        __half2 ph[8];
#pragma unroll
        for (int i = 0; i < 8; ++i)
            ph[i] = __floats2half2_rn(hr[2 * i] * din, hr[2 * i + 1] * din);
        int4* hp = reinterpret_cast<int4*>(hh + (size_t)node * H);
        hp[0] = *reinterpret_cast<int4*>(&ph[0]);
        hp[1] = *reinterpret_cast<int4*>(&ph[4]);
    }
}

// ---------------- fused gather conv2 + final GEMV + log_softmax; persistent, double-buffered feat ----------------
__global__ __launch_bounds__(256) void k_g2f(const int* __restrict__ ostart,
                                             const int* __restrict__ oend,
                                             const int* __restrict__ onode,
                                             const int* __restrict__ csr,
                                             const __half* __restrict__ hh,
                                             const float* __restrict__ dinv,
                                             const float* __restrict__ W2,
                                             const float* __restrict__ b2,
                                             float* __restrict__ out, int nG, int n) {
    __shared__ __align__(16) float w2t[40 * 20];
    __shared__ float b2s[40];
    __shared__ __align__(16) float feat[2][64 * 20];
    int t = threadIdx.x;
    for (int i = t; i < 640; i += 256) w2t[(i >> 4) * 20 + (i & 15)] = W2[(i & 15) * 40 + (i >> 4)];
    if (t < 40) b2s[t] = b2[t];
    int L = t & 3, p = L >> 1, jj = L & 1;
    int nl = t >> 2;
    int cb = (t & 3) * 10;
    const int4* tab = reinterpret_cast<const int4*>(hh);
    const v4i* csr4 = reinterpret_cast<const v4i*>(csr);
    int buf = 0;
    for (int gBase = blockIdx.x * 64; gBase < nG; gBase += GR * 64, buf ^= 1) {
        int g = gBase + nl;
        int node = __builtin_nontemporal_load(onode + g);
        float a[8];
#pragma unroll
        for (int k = 0; k < 8; ++k) a[k] = 0.0f;
        if (node >= 0) {
            int c  = (__builtin_nontemporal_load(ostart + g) >> 2) + (p << 1);
            int ce = __builtin_nontemporal_load(oend + g) >> 2;
            v4i e0 = (v4i){0, 0, 0, 0}, e1 = e0;
            if (c < ce) { e0 = __builtin_nontemporal_load(csr4 + c); e1 = __builtin_nontemporal_load(csr4 + c + 1); }
            while (c < ce) {
                v4i f0 = e0, f1 = e1;
                c += 4;
                if (c < ce) { e0 = __builtin_nontemporal_load(csr4 + c); e1 = __builtin_nontemporal_load(csr4 + c + 1); }
                int4 g0 = tab[(size_t)f0.x * 2 + jj];
                int4 g1 = tab[(size_t)f0.y * 2 + jj];
                int4 g2 = tab[(size_t)f0.z * 2 + jj];
                int4 g3 = tab[(size_t)f0.w * 2 + jj];
                int4 g4 = tab[(size_t)f1.x * 2 + jj];
                int4 g5 = tab[(size_t)f1.y * 2 + jj];
                int4 g6 = tab[(size_t)f1.z * 2 + jj];
                int4 g7 = tab[(size_t)f1.w * 2 + jj];
                acc8(a, g0); acc8(a, g1); acc8(a, g2); acc8(a, g3);
                acc8(a, g4); acc8(a, g5); acc8(a, g6); acc8(a, g7);
            }
        }
#pragma unroll
        for (int k = 0; k < 8; ++k) a[k] += __shfl_xor(a[k], 2);
        if (node >= 0 && p == 0) {
            float din = dinv[node];
            int4 sv = tab[(size_t)node * 2 + jj];
            const __half2* h = reinterpret_cast<const __half2*>(&sv);
            float2 f0 = __half22float2(h[0]), f1 = __half22float2(h[1]);
            float2 f2 = __half22float2(h[2]), f3 = __half22float2(h[3]);
            float s8[8] = { f0.x, f0.y, f1.x, f1.y, f2.x, f2.y, f3.x, f3.y };
            float v[8];
#pragma unroll
            for (int k = 0; k < 8; ++k) v[k] = din * (a[k] + s8[k]);
            *reinterpret_cast<float4*>(&feat[buf][nl * 20 + jj * 8])     = make_float4(v[0], v[1], v[2], v[3]);
            *reinterpret_cast<float4*>(&feat[buf][nl * 20 + jj * 8 + 4]) = make_float4(v[4], v[5], v[6], v[7]);
        }
        __syncthreads();
        float4 f0 = *reinterpret_cast<const float4*>(&feat[buf][nl * 20]);
        float4 f1 = *reinterpret_cast<const float4*>(&feat[buf][nl * 20 + 4]);
        float4 f2 = *reinterpret_cast<const float4*>(&feat[buf][nl * 20 + 8]);
        float4 f3 = *reinterpret_cast<const float4*>(&feat[buf][nl * 20 + 12]);
        float z[10];
#pragma unroll
        for (int j = 0; j < 10; ++j) {
            const float4* wr = reinterpret_cast<const float4*>(&w2t[(cb + j) * 20]);
            float4 w0 = wr[0], w1 = wr[1], w2v = wr[2], w3 = wr[3];
            float acc = b2s[cb + j];
            acc = fmaf(f0.x, w0.x, acc); acc = fmaf(f0.y, w0.y, acc);
            acc = fmaf(f0.z, w0.z, acc); acc = fmaf(f0.w, w0.w, acc);
            acc = fmaf(f1.x, w1.x, acc); acc = fmaf(f1.y, w1.y, acc);
            acc = fmaf(f1.z, w1.z, acc); acc = fmaf(f1.w, w1.w, acc);
            acc = fmaf(f2.x, w2v.x, acc); acc = fmaf(f2.y, w2v.y, acc);
            acc = fmaf(f2.z, w2v.z, acc); acc = fmaf(f2.w, w2v.w, acc);
            acc = fmaf(f3.x, w3.x, acc); acc = fmaf(f3.y, w3.y, acc);
            acc = fmaf(f3.z, w3.z, acc); acc = fmaf(f3.w, w3.w, acc);
            z[j] = acc;
        }
        float m = z[0];
#pragma unroll
        for (int j = 1; j < 10; ++j) m = fmaxf(m, z[j]);
        m = fmaxf(m, __shfl_xor(m, 1));
        m = fmaxf(m, __shfl_xor(m, 2));
        float s = 0.0f;
#pragma unroll
        for (int j = 0; j < 10; ++j) s += expf(z[j] - m);
        s += __shfl_xor(s, 1);
        s += __shfl_xor(s, 2);
        float lse = m + logf(s);
        if (node >= 0) {
            float2* o = reinterpret_cast<float2*>(out + (size_t)node * 40 + cb);
#pragma unroll
            for (int j = 0; j < 5; ++j)
                o[j] = make_float2(z[2 * j] - lse, z[2 * j + 1] - lse);
        }
    }
}

extern "C" void kernel_launch(void* const* d_in, const int* in_sizes, int n_in,
                              void* d_out, int out_size, void* d_ws, size_t ws_size,
                              hipStream_t stream) {
    const float* x     = (const float*)d_in[0];
    const int*   src   = (const int*)d_in[1];
    const int*   dst   = (const int*)d_in[2];
    const float* W1    = (const float*)d_in[3];
    const float* b1    = (const float*)d_in[4];
    const float* gamma = (const float*)d_in[5];
    const float* beta  = (const float*)d_in[6];
    const float* Wl    = (const float*)d_in[7];
    const float* bl    = (const float*)d_in[8];
    const float* W2    = (const float*)d_in[9];
    const float* b2    = (const float*)d_in[10];
    float* out = (float*)d_out;

    int n = in_sizes[0] / F_IN;   // 100000
    int e = in_sizes[1];          // 3200000
    int nbkt = (n + RB - 1) >> RB_BITS;   // 391
    int nAlign = (n + 15) & ~15;
    int nG = nbkt * RB;                                      // ordered-node slots
    size_t bktB = (size_t)nbkt << CAPB_BITS;                 // fixed-capacity entries (temp & csr)
    size_t hTileB = (size_t)nAlign * H * 4;                  // 6.4 MB
    size_t unionB = bktB * 4;                                // temp (25.6 MB)
    if (unionB < hTileB) unionB = hTileB;                    // also holds hbuf later

    char* wsb = (char*)d_ws;
    int*    csr      = (int*)wsb;      wsb += (bktB + 64) * 4;
    char*   uni      = wsb;            wsb += unionB;
    int*    temp     = (int*)uni;                  // alive: k_bin .. k_sort
    float*  hbuf     = (float*)uni;                // alive: k_gather1 .. k_hops
    int*    ostart   = (int*)wsb;      wsb += (size_t)(nG + 16) * 4;
    int*    oend     = (int*)wsb;      wsb += (size_t)(nG + 16) * 4;
    int*    onode    = (int*)wsb;      wsb += (size_t)(nG + 16) * 4;
    float*  dinv     = (float*)wsb;    wsb += (size_t)nAlign * 4;
    int*    gcur     = (int*)wsb;      wsb += NBKT_MAX * 4;
    float*  stats    = (float*)wsb;    wsb += 64 * 4;
    __half* h1h      = (__half*)wsb;   wsb += (size_t)(nAlign + NDUMMY + 16) * H * 2;
    __half* hh       = (__half*)wsb;   wsb += (size_t)(nAlign + NDUMMY + 16) * H * 2;

    k_zero<<<64, 256, 0, stream>>>(gcur, stats, h1h, hh, n);
    k_bin<<<(e + BIN_CHUNK - 1) / BIN_CHUNK, 512, 0, stream>>>(src, dst, gcur, temp, e);
    k_sort<<<nbkt, 512, 0, stream>>>(gcur, temp, csr, ostart, oend, onode, dinv, n);
    k_mm1<<<(n + 15) / 16, 256, 0, stream>>>(x, W1, dinv, h1h, n);
    k_gather1<<<GR, 256, 0, stream>>>(ostart, oend, onode, csr, h1h, dinv, b1, hbuf, stats, nG, n);
    k_hops<<<(n + 255) / 256, 256, 0, stream>>>(hbuf, hh, stats, gamma, beta, Wl, bl, dinv, n, (float)n);
    k_g2f<<<GR, 256, 0, stream>>>(ostart, oend, onode, csr, hh, dinv, W2, b2, out, nG, n);
}

// Round 11
// 261.285 us; speedup vs baseline: 1.0105x; 1.0105x over previous
//
#include <hip/hip_runtime.h>
#include <hip/hip_fp16.h>
#include <math.h>

#define F_IN 128
#define H 16
#define C 40
#define K_HOPS 10
#define ALPHA 0.1f
#define BN_EPS 1e-5f

#define RB 256          // nodes per bucket
#define RB_BITS 8
#define NBKT_MAX 512    // ceil(100000/256)=391
#define SRC_MASK 0x1FFFF
#define PADQ 16         // node segment padded to multiple of 16 entries
#define NDUMMY 2048     // dummy zero rows spread over L2
#define CAPB_BITS 14    // fixed per-bucket capacity for temp AND csr (16384 entries)
#define CAPB (1 << CAPB_BITS)
#define STAGE_CAP 14336 // ints (56 KB) LDS staging for csr scatter

typedef int v4i __attribute__((ext_vector_type(4)));

// ---------------- zero: gcur = bucket bases, stats=0, dummy rows of both tables = 0 ----------------
__global__ void k_zero(int* __restrict__ gcur, float* __restrict__ stats,
                       __half* __restrict__ h1h, __half* __restrict__ hh, int n) {
    int id = blockIdx.x * blockDim.x + threadIdx.x;
    if (id < NBKT_MAX) gcur[id] = id << CAPB_BITS;
    if (id < 32) stats[id] = 0.0f;
    int* z1 = (int*)(h1h + (size_t)n * H);
    int* z2 = (int*)(hh + (size_t)n * H);
    if (id < NDUMMY * H / 2) { z1[id] = 0; z2[id] = 0; }
}

// ---------------- bin edges: LDS counting sort per block -> dense run writes ----------------
#define BIN_CHUNK 4096
__global__ __launch_bounds__(512) void k_bin(const int* __restrict__ src,
                                             const int* __restrict__ dst,
                                             int* __restrict__ gcur,
                                             int* __restrict__ temp, int e) {
    __shared__ int hist[NBKT_MAX];
    __shared__ int cur[NBKT_MAX];
    __shared__ int gofs[NBKT_MAX];
    __shared__ int wsum[8];
    __shared__ int stageV[BIN_CHUNK];
    __shared__ int stageD[BIN_CHUNK];
    int t = threadIdx.x;
    hist[t] = 0;
    __syncthreads();
    int base = blockIdx.x * BIN_CHUNK;
    int cnt = e - base; if (cnt > BIN_CHUNK) cnt = BIN_CHUNK;
    const v4i* s4 = reinterpret_cast<const v4i*>(src + base);
    const v4i* d4 = reinterpret_cast<const v4i*>(dst + base);
    v4i sv[2], dv[2];
#pragma unroll
    for (int i = 0; i < 2; ++i) {
        int e0 = (t * 2 + i) * 4;
        if (e0 + 3 < cnt) { sv[i] = s4[t * 2 + i]; dv[i] = d4[t * 2 + i]; }
        else if (e0 < cnt) {
            int ts[4], td[4];
#pragma unroll
            for (int j = 0; j < 4; ++j) {
                int ei = e0 + j;
                ts[j] = (ei < cnt) ? src[base + ei] : 0;
                td[j] = (ei < cnt) ? dst[base + ei] : -1;
            }
            sv[i] = *reinterpret_cast<v4i*>(ts); dv[i] = *reinterpret_cast<v4i*>(td);
        } else { dv[i] = (v4i){-1, -1, -1, -1}; sv[i] = dv[i]; }
    }
#pragma unroll
    for (int i = 0; i < 2; ++i) {
        if (dv[i].x >= 0) atomicAdd(&hist[dv[i].x >> RB_BITS], 1);
        if (dv[i].y >= 0) atomicAdd(&hist[dv[i].y >> RB_BITS], 1);
        if (dv[i].z >= 0) atomicAdd(&hist[dv[i].z >> RB_BITS], 1);
        if (dv[i].w >= 0) atomicAdd(&hist[dv[i].w >> RB_BITS], 1);
    }
    __syncthreads();
    int v = hist[t];
    int lane = t & 63, wv = t >> 6;
    int s = v;
#pragma unroll
    for (int off = 1; off < 64; off <<= 1) { int u = __shfl_up(s, off); if (lane >= off) s += u; }
    if (lane == 63) wsum[wv] = s;
    __syncthreads();
    if (t < 8) {
        int x = wsum[t];
#pragma unroll
        for (int off = 1; off < 8; off <<= 1) { int u = __shfl_up(x, off); if (t >= off) x += u; }
        wsum[t] = x;
    }
    __syncthreads();
    int excl = s - v + (wv ? wsum[wv - 1] : 0);
    cur[t] = excl;
    int g = v ? atomicAdd(&gcur[t], v) : 0;
    gofs[t] = g - excl;
    __syncthreads();
#pragma unroll
    for (int i = 0; i < 2; ++i) {
        int ds[4] = { dv[i].x, dv[i].y, dv[i].z, dv[i].w };
        int ssx[4] = { sv[i].x, sv[i].y, sv[i].z, sv[i].w };
#pragma unroll
        for (int j = 0; j < 4; ++j) {
            int d = ds[j];
            if (d >= 0) {
                int b = d >> RB_BITS;
                int pos = atomicAdd(&cur[b], 1);
                stageV[pos] = ssx[j] | ((d & (RB - 1)) << 17);
                stageD[pos] = gofs[b];
            }
        }
    }
    __syncthreads();
    for (int i = t; i < cnt; i += 512)
        temp[stageD[i] + i] = stageV[i];
}

// ---------------- per-bucket counting sort -> padded CSR (LDS-staged scatter);
//                  512 threads; deg->dinv; HEAVY-FIRST order ----------------
__global__ __launch_bounds__(512) void k_sort(const int* __restrict__ gcur,
                                              const int* __restrict__ temp,
                                              int* __restrict__ csr,
                                              int* __restrict__ ostart,
                                              int* __restrict__ oend,
                                              int* __restrict__ onode,
                                              float* __restrict__ dinv, int n) {
    __shared__ int hist[RB];
    __shared__ int cur[RB];
    __shared__ int wsum[4];
    __shared__ int qh[64];
    __shared__ int qb[64];
    __shared__ int ptotS;
    __shared__ int stage[STAGE_CAP];
    int t = threadIdx.x;
    int bkt = blockIdx.x;
    int start = bkt << CAPB_BITS;
    int endi = gcur[bkt];
    int nv = endi - start;
    int n4 = nv >> 2;
    const v4i* t4 = reinterpret_cast<const v4i*>(temp + start);
    if (t < RB) hist[t] = 0;
    if (t < 64) qh[t] = 0;
    __syncthreads();
    for (int k = t; k < n4; k += 512) {
        v4i v = t4[k];
        atomicAdd(&hist[v.x >> 17], 1);
        atomicAdd(&hist[v.y >> 17], 1);
        atomicAdd(&hist[v.z >> 17], 1);
        atomicAdd(&hist[v.w >> 17], 1);
    }
    for (int k = start + (n4 << 2) + t; k < endi; k += 512)
        atomicAdd(&hist[temp[k] >> 17], 1);
    __syncthreads();
    int node = (bkt << RB_BITS) + t;
    int h = 0, pv = 0;
    bool va = false;
    if (t < RB) {
        h = hist[t];
        pv = (h + PADQ - 1) & ~(PADQ - 1);
        va = (node < n);
        if (va) dinv[node] = rsqrtf((float)(h + 1));
    }
    int lane = t & 63, wv = t >> 6;
    int s = pv;
#pragma unroll
    for (int off = 1; off < 64; off <<= 1) { int u = __shfl_up(s, off); if (lane >= off) s += u; }
    if (lane == 63 && wv < 4) wsum[wv] = s;
    __syncthreads();
    if (t < 4) {
        int x = wsum[t];
#pragma unroll
        for (int off = 1; off < 4; off <<= 1) { int u = __shfl_up(x, off); if (t >= off) x += u; }
        wsum[t] = x;
        if (t == 3) ptotS = x;
    }
    __syncthreads();
    int pexcl = 0, s0 = 0, q = 63, r = 0;
    if (t < RB) {
        pexcl = s - pv + (wv ? wsum[wv - 1] : 0);
        s0 = start + pexcl;
        q = 63 - min(pv >> 4, 63);
        r = atomicAdd(&qh[q], 1);
    }
    __syncthreads();
    int ptotal = ptotS;
    if (t == 0) {
        int run = 0;
        for (int i = 0; i < 64; ++i) { qb[i] = run; run += qh[i]; }
    }
    __syncthreads();
    if (t < RB) {
        int ga = (bkt << RB_BITS) + qb[q] + r;
        ostart[ga] = s0; oend[ga] = s0 + pv; onode[ga] = va ? node : -1;
    }
    if (ptotal <= STAGE_CAP) {
        if (t < RB) cur[t] = pexcl;
        for (int i = t; i < ptotal; i += 512) stage[i] = -1;
        __syncthreads();
        for (int k = t; k < n4; k += 512) {
            v4i v = t4[k];
            int p0 = atomicAdd(&cur[v.x >> 17], 1); stage[p0] = v.x & SRC_MASK;
            int p1 = atomicAdd(&cur[v.y >> 17], 1); stage[p1] = v.y & SRC_MASK;
            int p2 = atomicAdd(&cur[v.z >> 17], 1); stage[p2] = v.z & SRC_MASK;
            int p3 = atomicAdd(&cur[v.w >> 17], 1); stage[p3] = v.w & SRC_MASK;
        }
        for (int k = start + (n4 << 2) + t; k < endi; k += 512) {
            int v = temp[k];
            int pos = atomicAdd(&cur[v >> 17], 1);
            stage[pos] = v & SRC_MASK;
        }
        __syncthreads();
        for (int i = t * 4; i < ptotal; i += 2048) {
            v4i v = *reinterpret_cast<const v4i*>(&stage[i]);
            int gi = start + i;
            v.x = (v.x < 0) ? n + ((gi + 0) & (NDUMMY - 1)) : v.x;
            v.y = (v.y < 0) ? n + ((gi + 1) & (NDUMMY - 1)) : v.y;
            v.z = (v.z < 0) ? n + ((gi + 2) & (NDUMMY - 1)) : v.z;
            v.w = (v.w < 0) ? n + ((gi + 3) & (NDUMMY - 1)) : v.w;
            *reinterpret_cast<v4i*>(&csr[gi]) = v;
        }
    } else {
        if (t < RB) cur[t] = s0;
        __syncthreads();
        for (int k = start + t; k < endi; k += 512) {
            int v = temp[k];
            int pos = atomicAdd(&cur[v >> 17], 1);
            csr[pos] = v & SRC_MASK;
        }
        __syncthreads();
        if (t < RB) for (int i = s0 + h; i < s0 + pv; ++i) csr[i] = n + (i & (NDUMMY - 1));
    }
}

// ---------------- h1' = dinv .* (x @ W1) -> fp16 table ----------------
__global__ __launch_bounds__(256) void k_mm1(const float* __restrict__ x,
                                             const float* __restrict__ W1,
                                             const float* __restrict__ dinv,
                                             __half* __restrict__ h1h, int n) {
    __shared__ __align__(16) float xs[16 * 132];
    __shared__ __align__(16) float ws[128 * 16];
    int t = threadIdx.x;
    int node0 = blockIdx.x * 16;
    const float4* x4 = reinterpret_cast<const float4*>(x);
    const float4* w4 = reinterpret_cast<const float4*>(W1);
#pragma unroll
    for (int r = 0; r < 2; ++r) {
        int f = t + r * 256;
        int nl = f >> 5, k4 = f & 31;
        int nn = node0 + nl; if (nn >= n) nn = n - 1;
        *reinterpret_cast<float4*>(&xs[nl * 132 + k4 * 4]) = x4[(size_t)nn * 32 + k4];
        *reinterpret_cast<float4*>(&ws[f * 4]) = w4[f];
    }
    __syncthreads();
    int nl = t >> 4, j = t & 15;
    float acc = 0.0f;
#pragma unroll 8
    for (int k = 0; k < 128; ++k)
        acc = fmaf(xs[nl * 132 + k], ws[k * 16 + j], acc);
    int node = node0 + nl;
    if (node < n) h1h[(size_t)node * H + j] = __float2half(acc * dinv[node]);
}

__device__ __forceinline__ void acc8(float* a, int4 gv) {
    const __half2* h = reinterpret_cast<const __half2*>(&gv);
    float2 f0 = __half22float2(h[0]);
    float2 f1 = __half22float2(h[1]);
    float2 f2 = __half22float2(h[2]);
    float2 f3 = __half22float2(h[3]);
    a[0] += f0.x; a[1] += f0.y; a[2] += f1.x; a[3] += f1.y;
    a[4] += f2.x; a[5] += f2.y; a[6] += f3.x; a[7] += f3.y;
}

// ---------------- gather conv1: 4 lanes/node (2 pairs), csr prefetch pipeline;
//                  heavy-first order; + bias + ReLU + BN stats ----------------
__global__ __launch_bounds__(256) void k_gather1(const int* __restrict__ ostart,
                                                 const int* __restrict__ oend,
                                                 const int* __restrict__ onode,
                                                 const int* __restrict__ csr,
                                                 const __half* __restrict__ h1h,
                                                 const float* __restrict__ dinv,
                                                 const float* __restrict__ b1,
                                                 float* __restrict__ hout,
                                                 float* __restrict__ stats, int n) {
    __shared__ float sm[32];
    __shared__ float b1s[16];
    int t = threadIdx.x;
    if (t < 32) sm[t] = 0.0f;
    if (t < 16) b1s[t] = b1[t];
    __syncthreads();
    int idx = blockIdx.x * 256 + t;
    int g = idx >> 2;
    int L = idx & 3, p = L >> 1, jj = L & 1;
    int node = __builtin_nontemporal_load(onode + g);
    float a[8];
#pragma unroll
    for (int k = 0; k < 8; ++k) a[k] = 0.0f;
    const int4* tab = reinterpret_cast<const int4*>(h1h);
    if (node >= 0) {
        int c  = (__builtin_nontemporal_load(ostart + g) >> 2) + (p << 1);
        int ce = __builtin_nontemporal_load(oend + g) >> 2;
        const v4i* csr4 = reinterpret_cast<const v4i*>(csr);
        v4i e0 = (v4i){0, 0, 0, 0}, e1 = e0;
        if (c < ce) { e0 = __builtin_nontemporal_load(csr4 + c); e1 = __builtin_nontemporal_load(csr4 + c + 1); }
        while (c < ce) {
            v4i f0 = e0, f1 = e1;
            c += 4;
            if (c < ce) { e0 = __builtin_nontemporal_load(csr4 + c); e1 = __builtin_nontemporal_load(csr4 + c + 1); }
            int4 g0 = tab[(size_t)f0.x * 2 + jj];
            int4 g1 = tab[(size_t)f0.y * 2 + jj];
            int4 g2 = tab[(size_t)f0.z * 2 + jj];
            int4 g3 = tab[(size_t)f0.w * 2 + jj];
            int4 g4 = tab[(size_t)f1.x * 2 + jj];
            int4 g5 = tab[(size_t)f1.y * 2 + jj];
            int4 g6 = tab[(size_t)f1.z * 2 + jj];
            int4 g7 = tab[(size_t)f1.w * 2 + jj];
            acc8(a, g0); acc8(a, g1); acc8(a, g2); acc8(a, g3);
            acc8(a, g4); acc8(a, g5); acc8(a, g6); acc8(a, g7);
        }
    }
#pragma unroll
    for (int k = 0; k < 8; ++k) a[k] += __shfl_xor(a[k], 2);
    float din = 0.0f;
    int4 sv = make_int4(0, 0, 0, 0);
    if (node >= 0) {
        din = dinv[node];
        sv = tab[(size_t)node * 2 + jj];
    }
    float v[8];
    {
        const __half2* h = reinterpret_cast<const __half2*>(&sv);
        float2 f0 = __half22float2(h[0]), f1 = __half22float2(h[1]);
        float2 f2 = __half22float2(h[2]), f3 = __half22float2(h[3]);
        float s8[8] = { f0.x, f0.y, f1.x, f1.y, f2.x, f2.y, f3.x, f3.y };
        bool writer = (node >= 0) && (p == 0);
#pragma unroll
        for (int k = 0; k < 8; ++k) {
            float val = fmaxf(din * (a[k] + s8[k]) + b1s[jj * 8 + k], 0.0f);
            v[k] = writer ? val : 0.0f;
        }
        if (writer) {
            float4* o = reinterpret_cast<float4*>(hout + (size_t)node * H + jj * 8);
            o[0] = make_float4(v[0], v[1], v[2], v[3]);
            o[1] = make_float4(v[4], v[5], v[6], v[7]);
        }
    }
#pragma unroll
    for (int k = 0; k < 8; ++k) {
        float s1 = v[k], s2 = v[k] * v[k];
        s1 += __shfl_xor(s1, 2);  s2 += __shfl_xor(s2, 2);
        s1 += __shfl_xor(s1, 4);  s2 += __shfl_xor(s2, 4);
        s1 += __shfl_xor(s1, 8);  s2 += __shfl_xor(s2, 8);
        s1 += __shfl_xor(s1, 16); s2 += __shfl_xor(s2, 16);
        s1 += __shfl_xor(s1, 32); s2 += __shfl_xor(s2, 32);
        if ((t & 63) < 2) {
            atomicAdd(&sm[jj * 8 + k], s1);
            atomicAdd(&sm[16 + jj * 8 + k], s2);
        }
    }
    __syncthreads();
    if (t < 32) atomicAdd(&stats[t], sm[t]);
}

// ---------------- BN(coef inline) apply + K_HOPS residual blocks -> scaled fp16 table ----------------
__global__ __launch_bounds__(256) void k_hops(const float* __restrict__ h,
                                              __half* __restrict__ hh,
                                              const float* __restrict__ stats,
                                              const float* __restrict__ gamma,
                                              const float* __restrict__ beta,
                                              const float* __restrict__ Wl,
                                              const float* __restrict__ bl,
                                              const float* __restrict__ dinv, int n, float nf) {
    __shared__ float wl[256], bls[16], av[16], cv[16];
    int t = threadIdx.x;
    wl[t] = Wl[(t & 15) * 16 + (t >> 4)];
    if (t < 16) {
        bls[t] = bl[t];
        float mean = stats[t] / nf;
        float var = stats[16 + t] / nf - mean * mean;
        float aa = gamma[t] * rsqrtf(var + BN_EPS);
        av[t] = aa;
        cv[t] = beta[t] - mean * aa;
    }
    __syncthreads();
    int node = blockIdx.x * 256 + t;
    if (node >= n) return;
    float hr[16];
    {
        const float4* hp = reinterpret_cast<const float4*>(h + (size_t)node * H);
        float4 v0 = hp[0], v1 = hp[1], v2 = hp[2], v3 = hp[3];
        hr[0] = v0.x; hr[1] = v0.y; hr[2] = v0.z; hr[3] = v0.w;
        hr[4] = v1.x; hr[5] = v1.y; hr[6] = v1.z; hr[7] = v1.w;
        hr[8] = v2.x; hr[9] = v2.y; hr[10] = v2.z; hr[11] = v2.w;
        hr[12] = v3.x; hr[13] = v3.y; hr[14] = v3.z; hr[15] = v3.w;
    }
#pragma unroll
    for (int j = 0; j < 16; ++j) hr[j] = hr[j] * av[j] + cv[j];
    for (int it = 0; it < K_HOPS; ++it) {
        float tmp[16];
#pragma unroll
        for (int j = 0; j < 16; ++j) {
            float a = bls[j];
#pragma unroll
            for (int k = 0; k < 16; ++k) a = fmaf(hr[k], wl[j * 16 + k], a);
            tmp[j] = fmaxf(a, 0.0f);
        }
#pragma unroll
        for (int j = 0; j < 16; ++j) hr[j] = ALPHA * tmp[j] + (1.0f - ALPHA) * hr[j];
    }
    {
        float din = dinv[node];
        __half2 ph[8];
#pragma unroll
        for (int i = 0; i < 8; ++i)
            ph[i] = __floats2half2_rn(hr[2 * i] * din, hr[2 * i + 1] * din);
        int4* hp = reinterpret_cast<int4*>(hh + (size_t)node * H);
        hp[0] = *reinterpret_cast<int4*>(&ph[0]);
        hp[1] = *reinterpret_cast<int4*>(&ph[4]);
    }
}

// ---------------- fused gather conv2 + final GEMV + log_softmax; csr prefetch pipeline ----------------
__global__ __launch_bounds__(256) void k_g2f(const int* __restrict__ ostart,
                                             const int* __restrict__ oend,
                                             const int* __restrict__ onode,
                                             const int* __restrict__ csr,
                                             const __half* __restrict__ hh,
                                             const float* __restrict__ dinv,
                                             const float* __restrict__ W2,
                                             const float* __restrict__ b2,
                                             float* __restrict__ out, int n) {
    __shared__ __align__(16) float w2t[40 * 20];
    __shared__ float b2s[40];
    __shared__ __align__(16) float feat[64 * 20];
    int t = threadIdx.x;
    for (int i = t; i < 640; i += 256) w2t[(i >> 4) * 20 + (i & 15)] = W2[(i & 15) * 40 + (i >> 4)];
    if (t < 40) b2s[t] = b2[t];
    int idx = blockIdx.x * 256 + t;
    int g = idx >> 2;
    int L = idx & 3, p = L >> 1, jj = L & 1;
    int node = __builtin_nontemporal_load(onode + g);
    float a[8];
#pragma unroll
    for (int k = 0; k < 8; ++k) a[k] = 0.0f;
    const int4* tab = reinterpret_cast<const int4*>(hh);
    if (node >= 0) {
        int c  = (__builtin_nontemporal_load(ostart + g) >> 2) + (p << 1);
        int ce = __builtin_nontemporal_load(oend + g) >> 2;
        const v4i* csr4 = reinterpret_cast<const v4i*>(csr);
        v4i e0 = (v4i){0, 0, 0, 0}, e1 = e0;
        if (c < ce) { e0 = __builtin_nontemporal_load(csr4 + c); e1 = __builtin_nontemporal_load(csr4 + c + 1); }
        while (c < ce) {
            v4i f0 = e0, f1 = e1;
            c += 4;
            if (c < ce) { e0 = __builtin_nontemporal_load(csr4 + c); e1 = __builtin_nontemporal_load(csr4 + c + 1); }
            int4 g0 = tab[(size_t)f0.x * 2 + jj];
            int4 g1 = tab[(size_t)f0.y * 2 + jj];
            int4 g2 = tab[(size_t)f0.z * 2 + jj];
            int4 g3 = tab[(size_t)f0.w * 2 + jj];
            int4 g4 = tab[(size_t)f1.x * 2 + jj];
            int4 g5 = tab[(size_t)f1.y * 2 + jj];
            int4 g6 = tab[(size_t)f1.z * 2 + jj];
            int4 g7 = tab[(size_t)f1.w * 2 + jj];
            acc8(a, g0); acc8(a, g1); acc8(a, g2); acc8(a, g3);
            acc8(a, g4); acc8(a, g5); acc8(a, g6); acc8(a, g7);
        }
    }
#pragma unroll
    for (int k = 0; k < 8; ++k) a[k] += __shfl_xor(a[k], 2);
    int nl = t >> 2;
    if (node >= 0 && p == 0) {
        float din = dinv[node];
        int4 sv = tab[(size_t)node * 2 + jj];
        const __half2* h = reinterpret_cast<const __half2*>(&sv);
        float2 f0 = __half22float2(h[0]), f1 = __half22float2(h[1]);
        float2 f2 = __half22float2(h[2]), f3 = __half22float2(h[3]);
        float s8[8] = { f0.x, f0.y, f1.x, f1.y, f2.x, f2.y, f3.x, f3.y };
        float v[8];
#pragma unroll
        for (int k = 0; k < 8; ++k) v[k] = din * (a[k] + s8[k]);
        *reinterpret_cast<float4*>(&feat[nl * 20 + jj * 8])     = make_float4(v[0], v[1], v[2], v[3]);
        *reinterpret_cast<float4*>(&feat[nl * 20 + jj * 8 + 4]) = make_float4(v[4], v[5], v[6], v[7]);
    }
    __syncthreads();
    float4 f0 = *reinterpret_cast<const float4*>(&feat[nl * 20]);
    float4 f1 = *reinterpret_cast<const float4*>(&feat[nl * 20 + 4]);
    float4 f2 = *reinterpret_cast<const float4*>(&feat[nl * 20 + 8]);
    float4 f3 = *reinterpret_cast<const float4*>(&feat[nl * 20 + 12]);
    int cb = (t & 3) * 10;
    float z[10];
#pragma unroll
    for (int j = 0; j < 10; ++j) {
        const float4* wr = reinterpret_cast<const float4*>(&w2t[(cb + j) * 20]);
        float4 w0 = wr[0], w1 = wr[1], w2v = wr[2], w3 = wr[3];
        float acc = b2s[cb + j];
        acc = fmaf(f0.x, w0.x, acc); acc = fmaf(f0.y, w0.y, acc);
        acc = fmaf(f0.z, w0.z, acc); acc = fmaf(f0.w, w0.w, acc);
        acc = fmaf(f1.x, w1.x, acc); acc = fmaf(f1.y, w1.y, acc);
        acc = fmaf(f1.z, w1.z, acc); acc = fmaf(f1.w, w1.w, acc);
        acc = fmaf(f2.x, w2v.x, acc); acc = fmaf(f2.y, w2v.y, acc);
        acc = fmaf(f2.z, w2v.z, acc); acc = fmaf(f2.w, w2v.w, acc);
        acc = fmaf(f3.x, w3.x, acc); acc = fmaf(f3.y, w3.y, acc);
        acc = fmaf(f3.z, w3.z, acc); acc = fmaf(f3.w, w3.w, acc);
        z[j] = acc;
    }
    float m = z[0];
#pragma unroll
    for (int j = 1; j < 10; ++j) m = fmaxf(m, z[j]);
    m = fmaxf(m, __shfl_xor(m, 1));
    m = fmaxf(m, __shfl_xor(m, 2));
    float s = 0.0f;
#pragma unroll
    for (int j = 0; j < 10; ++j) s += expf(z[j] - m);
    s += __shfl_xor(s, 1);
    s += __shfl_xor(s, 2);
    float lse = m + logf(s);
    if (node >= 0) {
        float2* o = reinterpret_cast<float2*>(out + (size_t)node * 40 + cb);
#pragma unroll
        for (int j = 0; j < 5; ++j)
            o[j] = make_float2(z[2 * j] - lse, z[2 * j + 1] - lse);
    }
}

extern "C" void kernel_launch(void* const* d_in, const int* in_sizes, int n_in,
                              void* d_out, int out_size, void* d_ws, size_t ws_size,
                              hipStream_t stream) {
    const float* x     = (const float*)d_in[0];
    const int*   src   = (const int*)d_in[1];
    const int*   dst   = (const int*)d_in[2];
    const float* W1    = (const float*)d_in[3];
    const float* b1    = (const float*)d_in[4];
    const float* gamma = (const float*)d_in[5];
    const float* beta  = (const float*)d_in[6];
    const float* Wl    = (const float*)d_in[7];
    const float* bl    = (const float*)d_in[8];
    const float* W2    = (const float*)d_in[9];
    const float* b2    = (const float*)d_in[10];
    float* out = (float*)d_out;

    int n = in_sizes[0] / F_IN;   // 100000
    int e = in_sizes[1];          // 3200000
    int nbkt = (n + RB - 1) >> RB_BITS;   // 391
    int nAlign = (n + 15) & ~15;
    int nG = nbkt * RB;                                      // ordered-node slots
    size_t bktB = (size_t)nbkt << CAPB_BITS;                 // fixed-capacity entries (temp & csr)
    size_t hTileB = (size_t)nAlign * H * 4;                  // 6.4 MB
    size_t unionB = bktB * 4;                                // temp (25.6 MB)
    if (unionB < hTileB) unionB = hTileB;                    // also holds hbuf later

    char* wsb = (char*)d_ws;
    int*    csr      = (int*)wsb;      wsb += (bktB + 64) * 4;
    char*   uni      = wsb;            wsb += unionB;
    int*    temp     = (int*)uni;                  // alive: k_bin .. k_sort
    float*  hbuf     = (float*)uni;                // alive: k_gather1 .. k_hops
    int*    ostart   = (int*)wsb;      wsb += (size_t)(nG + 16) * 4;
    int*    oend     = (int*)wsb;      wsb += (size_t)(nG + 16) * 4;
    int*    onode    = (int*)wsb;      wsb += (size_t)(nG + 16) * 4;
    float*  dinv     = (float*)wsb;    wsb += (size_t)nAlign * 4;
    int*    gcur     = (int*)wsb;      wsb += NBKT_MAX * 4;
    float*  stats    = (float*)wsb;    wsb += 64 * 4;
    __half* h1h      = (__half*)wsb;   wsb += (size_t)(nAlign + NDUMMY + 16) * H * 2;
    __half* hh       = (__half*)wsb;   wsb += (size_t)(nAlign + NDUMMY + 16) * H * 2;

    k_zero<<<64, 256, 0, stream>>>(gcur, stats, h1h, hh, n);
    k_bin<<<(e + BIN_CHUNK - 1) / BIN_CHUNK, 512, 0, stream>>>(src, dst, gcur, temp, e);
    k_sort<<<nbkt, 512, 0, stream>>>(gcur, temp, csr, ostart, oend, onode, dinv, n);
    k_mm1<<<(n + 15) / 16, 256, 0, stream>>>(x, W1, dinv, h1h, n);
    k_gather1<<<nbkt * 4, 256, 0, stream>>>(ostart, oend, onode, csr, h1h, dinv, b1, hbuf, stats, n);
    k_hops<<<(n + 255) / 256, 256, 0, stream>>>(hbuf, hh, stats, gamma, beta, Wl, bl, dinv, n, (float)n);
    k_g2f<<<nbkt * 4, 256, 0, stream>>>(ostart, oend, onode, csr, hh, dinv, W2, b2, out, n);
}